// Round 6
// baseline (503.569 us; speedup 1.0000x reference)
//
#include <hip/hip_runtime.h>

// SFT/FiLM layer:
//   gamma = leaky(conv3x3(psi, gamma_w) + gamma_b)
//   beta  = leaky(conv3x3(psi, beta_w)  + beta_b)
//   out[b,h,w,band,c] = gamma[b,h,w,c]*x[b,h,w,band,c] + beta[b,h,w,c]
// x [2,128,128,32,64] f32, psi [2,128,128,64] f32, weights [3,3,64,64] f32.
//
// Fast path: tiny weight-split kernel + ONE fused kernel per 32-pixel strip:
//   phase 1: conv as bf16-split MFMA GEMM (a*w ~= ah*wh + al*wh + ah*wl),
//            psi hi/lo split done in-register during LDS staging (f32 source).
//            T14: next-tap weight loads issued BEFORE this tap's MFMA.
//   phase 2: gamma/beta parked in LDS (overlaid), stream x -> out (256 KB/blk)
//            with nontemporal loads/stores (keep wt/psi L2-resident).

#define LEAKY 0.3f

constexpr int Bc    = 2;
constexpr int Hc    = 128;
constexpr int Wc    = 128;
constexpr int BANDS = 32;
constexpr int C     = 64;
constexpr int CPSI  = 64;
constexpr int COUT2 = 128;           // gamma(64) || beta(64)
constexpr int NPIX  = Bc * Hc * Wc;  // 32768

typedef __attribute__((ext_vector_type(8))) short bf16x8;
typedef __attribute__((ext_vector_type(4))) float f32x4;

// ---- bf16 helpers (RNE) ---------------------------------------------------
__device__ __forceinline__ unsigned short f2bf(float v) {
  unsigned int u = __float_as_uint(v);
  u += 0x7fffu + ((u >> 16) & 1u);   // round-to-nearest-even
  return (unsigned short)(u >> 16);
}
__device__ __forceinline__ float bf2f(unsigned short h) {
  return __uint_as_float(((unsigned int)h) << 16);
}

// ---------------------------------------------------------------------------
// Preprocess: weights -> w_splitT [9][128 n][128 kp] bf16
//   n: 0..63 gamma cout, 64..127 beta cout.  kp: 0..63 hi(cin), 64..127 lo(cin)
// ---------------------------------------------------------------------------
__global__ __launch_bounds__(256) void split_w(
    const float* __restrict__ gw, const float* __restrict__ bw,
    unsigned short* __restrict__ wt)
{
  int o = blockIdx.x * 256 + threadIdx.x;        // 9*128*128 = 147456 threads
  int tap = o >> 14;
  int kp  = (o >> 7) & 127;
  int n   = o & 127;
  int cin = kp & 63;
  const float* src = (n < C) ? gw : bw;
  float v = src[((size_t)tap * 64 + cin) * 64 + (n & 63)];
  unsigned short hi = f2bf(v);
  unsigned short r  = (kp < 64) ? hi : f2bf(v - bf2f(hi));
  wt[((size_t)tap << 14) + (size_t)n * 128 + kp] = r;
}

// ---------------------------------------------------------------------------
// Fused kernel. Block = 32-pixel W-strip, 4 waves.
// Phase 1 (conv): wave = 32pix x 32cout via 2x2 frags of mfma 16x16x32 bf16.
//   LDS: As[3][34][136] psi halo (hi64|lo64 bf16), Bs[128][136] per-tap wts.
// Phase 2 (apply): g[32][132] f32 overlaid on As; stream 256 KB x -> out.
// ---------------------------------------------------------------------------
constexpr int AS_BYTES = 3 * 34 * 136 * 2;          // 27744
constexpr int BS_BYTES = 128 * 136 * 2;             // 34816
constexpr int SMEM_BYTES = AS_BYTES + BS_BYTES;     // 62560 -> 2 blocks/CU

__global__ __launch_bounds__(256) void sft_fused(
    const float* __restrict__ psi,           // raw f32 psi
    const unsigned short* __restrict__ wt,   // w_splitT
    const float* __restrict__ gbias, const float* __restrict__ bbias,
    const float* __restrict__ x,
    float* __restrict__ out)
{
  __shared__ __align__(16) char smem[SMEM_BYTES];
  auto As = (unsigned short(*)[34][136])smem;              // [3][34][136]
  auto Bs = (unsigned short(*)[136])(smem + AS_BYTES);     // [128][136]
  auto g  = (float(*)[132])smem;                           // [32][132] phase 2

  const int tid = threadIdx.x;
  const int blk = blockIdx.x;                   // 1024 blocks
  const int w0  = (blk & 3) * 32;
  const int h   = (blk >> 2) & 127;
  const int b   = blk >> 9;
  const int pix0 = blk * 32;                    // == (b*Hc+h)*Wc + w0

  // ---- stage psi halo strip (3 rows x 34 cols), f32 -> split bf16 hi|lo
  for (int c = tid; c < 3 * 34 * 16; c += 256) {
    int ch  = c & 15;                 // float4 chunk within 64-ch row
    int col = (c >> 4) % 34;
    int row = (c >> 4) / 34;
    int hh = h + row - 1;
    int ww = w0 + col - 1;
    float4 v = make_float4(0.f, 0.f, 0.f, 0.f);
    if (hh >= 0 && hh < Hc && ww >= 0 && ww < Wc)
      v = *(const float4*)&psi[(((size_t)b * Hc + hh) * Wc + ww) * CPSI + ch * 4];
    ushort4 hi, lo;
    hi.x = f2bf(v.x); lo.x = f2bf(v.x - bf2f(hi.x));
    hi.y = f2bf(v.y); lo.y = f2bf(v.y - bf2f(hi.y));
    hi.z = f2bf(v.z); lo.z = f2bf(v.z - bf2f(hi.z));
    hi.w = f2bf(v.w); lo.w = f2bf(v.w - bf2f(hi.w));
    *(ushort4*)&As[row][col][ch * 4]      = hi;
    *(ushort4*)&As[row][col][64 + ch * 4] = lo;
  }

  const int lane = tid & 63;
  const int wv   = tid >> 6;          // wave id 0..3
  const int nb   = wv * 32;           // wave's cout base
  const int lrow = lane & 15;
  const int lk8  = (lane >> 4) * 8;

  f32x4 acc[2][2];
#pragma unroll
  for (int i = 0; i < 2; ++i)
#pragma unroll
    for (int j = 0; j < 2; ++j) acc[i][j] = (f32x4){0.f, 0.f, 0.f, 0.f};

  // stage tap-0 weights
  for (int c = tid; c < 128 * 16; c += 256) {
    int ch = c & 15, n = c >> 4;
    *(int4*)&Bs[n][ch * 8] = *(const int4*)&wt[(size_t)n * 128 + ch * 8];
  }
  __syncthreads();

  for (int tap = 0; tap < 9; ++tap) {
    const int r  = tap / 3;
    const int dc = tap % 3;

    // ---- T14 issue-early: next-tap weight loads fly during this tap's MFMA.
    // (value-dep waits auto-inserted at the ds_write below; the barrier's
    //  vmcnt(0) drain lands exactly where the data is needed)
    int4 wreg[8];
    if (tap < 8) {
      const unsigned short* wsrc = wt + ((size_t)(tap + 1) << 14);
#pragma unroll
      for (int i = 0; i < 8; ++i) {
        int c = tid + 256 * i;                  // 0..2047 chunks
        int ch = c & 15, n = c >> 4;
        wreg[i] = *(const int4*)&wsrc[(size_t)n * 128 + ch * 8];
      }
    }

    // 3 compensation sub-blocks: (A hi,B hi), (A lo,B hi), (A hi,B lo)
#pragma unroll
    for (int sb = 0; sb < 3; ++sb) {
      const int ao = (sb == 1) ? 64 : 0;
      const int bo = (sb == 2) ? 64 : 0;
#pragma unroll
      for (int kk = 0; kk < 64; kk += 32) {
        bf16x8 af0 = *(const bf16x8*)&As[r][lrow + dc][ao + kk + lk8];
        bf16x8 af1 = *(const bf16x8*)&As[r][16 + lrow + dc][ao + kk + lk8];
        bf16x8 bf0 = *(const bf16x8*)&Bs[nb + lrow][bo + kk + lk8];
        bf16x8 bf1 = *(const bf16x8*)&Bs[nb + 16 + lrow][bo + kk + lk8];
        acc[0][0] = __builtin_amdgcn_mfma_f32_16x16x32_bf16(af0, bf0, acc[0][0], 0, 0, 0);
        acc[0][1] = __builtin_amdgcn_mfma_f32_16x16x32_bf16(af0, bf1, acc[0][1], 0, 0, 0);
        acc[1][0] = __builtin_amdgcn_mfma_f32_16x16x32_bf16(af1, bf0, acc[1][0], 0, 0, 0);
        acc[1][1] = __builtin_amdgcn_mfma_f32_16x16x32_bf16(af1, bf1, acc[1][1], 0, 0, 0);
      }
    }

    if (tap < 8) {
      __syncthreads();                 // everyone done reading Bs
#pragma unroll
      for (int i = 0; i < 8; ++i) {
        int c = tid + 256 * i;
        int ch = c & 15, n = c >> 4;
        *(int4*)&Bs[n][ch * 8] = wreg[i];
      }
      __syncthreads();
    }
  }

  // ---- epilogue: bias + leaky, park gamma/beta in LDS (overlaid on As)
  __syncthreads();                     // all MFMA input reads complete
#pragma unroll
  for (int nf = 0; nf < 2; ++nf) {
    const int n = nb + nf * 16 + lrow;
    const float bias = (n < C) ? gbias[n] : bbias[n - C];
#pragma unroll
    for (int mf = 0; mf < 2; ++mf) {
#pragma unroll
      for (int rr = 0; rr < 4; ++rr) {
        int m = mf * 16 + (lane >> 4) * 4 + rr;   // D: row=(lane>>4)*4+reg
        float v = acc[mf][nf][rr] + bias;         //    col=lane&15
        g[m][n] = v > 0.f ? v : LEAKY * v;
      }
    }
  }
  __syncthreads();

  // ---- phase 2: stream x -> out for the strip's 32 pixels (256 KB each way)
  // chunk idx4 = tid + 256*i: pixel = i>>1 (tid-invariant), channel offset
  // (4*idx4)&63 = (4*tid)&63 (iteration-invariant). Nontemporal: stream-once.
  const int c0 = (tid * 4) & 63;
  const size_t pbase = (size_t)pix0 * 2048 + (size_t)tid * 4;
#pragma unroll 4
  for (int p = 0; p < 32; ++p) {
    f32x4 ga = *(const f32x4*)&g[p][c0];
    f32x4 be = *(const f32x4*)&g[p][64 + c0];
    size_t a = pbase + (size_t)p * 2048;
    f32x4 x0 = __builtin_nontemporal_load((const f32x4*)&x[a]);
    f32x4 x1 = __builtin_nontemporal_load((const f32x4*)&x[a + 1024]);
    f32x4 o0, o1;
#pragma unroll
    for (int e = 0; e < 4; ++e) {
      o0[e] = fmaf(ga[e], x0[e], be[e]);
      o1[e] = fmaf(ga[e], x1[e], be[e]);
    }
    __builtin_nontemporal_store(o0, (f32x4*)&out[a]);
    __builtin_nontemporal_store(o1, (f32x4*)&out[a + 1024]);
  }
}

// ---------------------------------------------------------------------------
// Last-resort fallback (ws too small for even the 0.3 MB weight buffer):
// fused per-pixel conv + apply, zero workspace.
// ---------------------------------------------------------------------------
__global__ __launch_bounds__(256) void film_fused_slow(
    const float* __restrict__ psi,
    const float* __restrict__ gw, const float* __restrict__ gbias,
    const float* __restrict__ bw, const float* __restrict__ bbias,
    const float* __restrict__ x,
    float* __restrict__ out)
{
  const int pix = blockIdx.x;
  const int w = pix % Wc;
  const int h = (pix / Wc) % Hc;
  const int b = pix / (Wc * Hc);
  __shared__ float pshal[9 * CPSI];
  __shared__ float g[COUT2];
  const int t = threadIdx.x;

  if (t < 144) {
    int j = t * 4;
    int k = j % CPSI;
    int tap = j / CPSI;
    int r = tap / 3, s = tap % 3;
    int hh = h + r - 1, ww = w + s - 1;
    float4 v = make_float4(0.f, 0.f, 0.f, 0.f);
    if (hh >= 0 && hh < Hc && ww >= 0 && ww < Wc)
      v = *(const float4*)&psi[(((size_t)b * Hc + hh) * Wc + ww) * CPSI + k];
    *(float4*)&pshal[j] = v;
  }
  __syncthreads();

  if (t < COUT2) {
    int c = t & 63;
    const float* W_ = (t < C) ? gw : bw;
    float acc = (t < C) ? gbias[c] : bbias[c];
#pragma unroll 4
    for (int j = 0; j < 576; ++j) acc = fmaf(pshal[j], W_[(size_t)j * 64 + c], acc);
    g[t] = acc > 0.f ? acc : LEAKY * acc;
  }
  __syncthreads();

  const int coff = (t & 7) * 8;
  const size_t base = (size_t)pix * (BANDS * C) + (size_t)t * 8;
  float4 x0 = *(const float4*)&x[base];
  float4 x1 = *(const float4*)&x[base + 4];
  float4 ga0 = *(const float4*)&g[coff];
  float4 ga1 = *(const float4*)&g[coff + 4];
  float4 be0 = *(const float4*)&g[C + coff];
  float4 be1 = *(const float4*)&g[C + coff + 4];
  float4 o0, o1;
  o0.x = fmaf(ga0.x, x0.x, be0.x);
  o0.y = fmaf(ga0.y, x0.y, be0.y);
  o0.z = fmaf(ga0.z, x0.z, be0.z);
  o0.w = fmaf(ga0.w, x0.w, be0.w);
  o1.x = fmaf(ga1.x, x1.x, be1.x);
  o1.y = fmaf(ga1.y, x1.y, be1.y);
  o1.z = fmaf(ga1.z, x1.z, be1.z);
  o1.w = fmaf(ga1.w, x1.w, be1.w);
  *(float4*)&out[base] = o0;
  *(float4*)&out[base + 4] = o1;
}

extern "C" void kernel_launch(void* const* d_in, const int* in_sizes, int n_in,
                              void* d_out, int out_size, void* d_ws, size_t ws_size,
                              hipStream_t stream) {
  const float* x     = (const float*)d_in[0];
  const float* psi   = (const float*)d_in[1];
  const float* gw    = (const float*)d_in[2];
  const float* gbias = (const float*)d_in[3];
  const float* bw    = (const float*)d_in[4];
  const float* bbias = (const float*)d_in[5];
  float* out = (float*)d_out;

  const size_t wsplit_bytes = (size_t)9 * 128 * 128 * 2;   // 0.29 MB

  if (ws_size >= wsplit_bytes) {
    unsigned short* wtp = (unsigned short*)d_ws;
    split_w<<<9 * 128 * 128 / 256, 256, 0, stream>>>(gw, bw, wtp);
    sft_fused<<<NPIX / 32, 256, 0, stream>>>(psi, wtp, gbias, bbias, x, out);
  } else {
    film_fused_slow<<<NPIX, 256, 0, stream>>>(psi, gw, gbias, bw, bbias, x, out);
  }
}

// Round 8
// 464.704 us; speedup vs baseline: 1.0836x; 1.0836x over previous
//
#include <hip/hip_runtime.h>

// SFT/FiLM layer:
//   gamma = leaky(conv3x3(psi, gamma_w) + gamma_b)
//   beta  = leaky(conv3x3(psi, beta_w)  + beta_b)
//   out[b,h,w,band,c] = gamma[b,h,w,c]*x[b,h,w,band,c] + beta[b,h,w,c]
// x [2,128,128,32,64] f32, psi [2,128,128,64] f32, weights [3,3,64,64] f32.
//
// R6 counters: 169us, MfmaUtil 3.3 / VALUBusy 4.1 / Occ 19.4 / HBM 37% ->
// latency/occupancy-bound streaming at 2 blocks/CU (LDS 62.6KB).
// R7 fix: drop Bs from LDS (B-fragments direct from L2-resident wt, coalesced),
// overlay g on As -> LDS 27.7KB -> whole 1024-block grid co-resident (4/CU,
// 16 waves/CU); 9-tap MFMA loop now barrier-free.

#define LEAKY 0.3f

constexpr int Bc    = 2;
constexpr int Hc    = 128;
constexpr int Wc    = 128;
constexpr int BANDS = 32;
constexpr int C     = 64;
constexpr int CPSI  = 64;
constexpr int COUT2 = 128;           // gamma(64) || beta(64)
constexpr int NPIX  = Bc * Hc * Wc;  // 32768

typedef __attribute__((ext_vector_type(8))) short bf16x8;
typedef __attribute__((ext_vector_type(4))) float f32x4;

// ---- bf16 helpers (RNE) ---------------------------------------------------
__device__ __forceinline__ unsigned short f2bf(float v) {
  unsigned int u = __float_as_uint(v);
  u += 0x7fffu + ((u >> 16) & 1u);   // round-to-nearest-even
  return (unsigned short)(u >> 16);
}
__device__ __forceinline__ float bf2f(unsigned short h) {
  return __uint_as_float(((unsigned int)h) << 16);
}

// ---------------------------------------------------------------------------
// Preprocess: weights -> w_splitT [9][128 n][128 kp] bf16
//   n: 0..63 gamma cout, 64..127 beta cout.  kp: 0..63 hi(cin), 64..127 lo(cin)
// ---------------------------------------------------------------------------
__global__ __launch_bounds__(256) void split_w(
    const float* __restrict__ gw, const float* __restrict__ bw,
    unsigned short* __restrict__ wt)
{
  int o = blockIdx.x * 256 + threadIdx.x;        // 9*128*128 = 147456 threads
  int tap = o >> 14;
  int kp  = (o >> 7) & 127;
  int n   = o & 127;
  int cin = kp & 63;
  const float* src = (n < C) ? gw : bw;
  float v = src[((size_t)tap * 64 + cin) * 64 + (n & 63)];
  unsigned short hi = f2bf(v);
  unsigned short r  = (kp < 64) ? hi : f2bf(v - bf2f(hi));
  wt[((size_t)tap << 14) + (size_t)n * 128 + kp] = r;
}

// ---------------------------------------------------------------------------
// Fused kernel. Block = 32-pixel W-strip, 4 waves.
// Phase 1 (conv): wave = 32pix x 32cout via 2x2 frags of mfma 16x16x32 bf16.
//   LDS: As[3][34][136] psi halo (hi64|lo64 bf16) ONLY. B-frags from global
//   (wt is 288KB, L2-resident, each frag-load is 64B-line coalesced).
// Phase 2 (apply): g[32][132] f32 overlaid on As; stream 256 KB x -> out.
// ---------------------------------------------------------------------------
constexpr int SMEM_BYTES = 3 * 34 * 136 * 2;        // 27744 -> 4-5 blocks/CU

__global__ __launch_bounds__(256, 4) void sft_fused(
    const float* __restrict__ psi,           // raw f32 psi
    const unsigned short* __restrict__ wt,   // w_splitT
    const float* __restrict__ gbias, const float* __restrict__ bbias,
    const float* __restrict__ x,
    float* __restrict__ out)
{
  __shared__ __align__(16) char smem[SMEM_BYTES];
  auto As = (unsigned short(*)[34][136])smem;              // [3][34][136]
  auto g  = (float(*)[132])smem;                           // [32][132] phase 2

  const int tid = threadIdx.x;
  const int blk = blockIdx.x;                   // 1024 blocks
  const int w0  = (blk & 3) * 32;
  const int h   = (blk >> 2) & 127;
  const int b   = blk >> 9;
  const int pix0 = blk * 32;                    // == (b*Hc+h)*Wc + w0

  // ---- stage psi halo strip (3 rows x 34 cols), f32 -> split bf16 hi|lo
  for (int c = tid; c < 3 * 34 * 16; c += 256) {
    int ch  = c & 15;                 // float4 chunk within 64-ch row
    int col = (c >> 4) % 34;
    int row = (c >> 4) / 34;
    int hh = h + row - 1;
    int ww = w0 + col - 1;
    float4 v = make_float4(0.f, 0.f, 0.f, 0.f);
    if (hh >= 0 && hh < Hc && ww >= 0 && ww < Wc)
      v = *(const float4*)&psi[(((size_t)b * Hc + hh) * Wc + ww) * CPSI + ch * 4];
    ushort4 hi, lo;
    hi.x = f2bf(v.x); lo.x = f2bf(v.x - bf2f(hi.x));
    hi.y = f2bf(v.y); lo.y = f2bf(v.y - bf2f(hi.y));
    hi.z = f2bf(v.z); lo.z = f2bf(v.z - bf2f(hi.z));
    hi.w = f2bf(v.w); lo.w = f2bf(v.w - bf2f(hi.w));
    *(ushort4*)&As[row][col][ch * 4]      = hi;
    *(ushort4*)&As[row][col][64 + ch * 4] = lo;
  }

  const int lane = tid & 63;
  const int wv   = tid >> 6;          // wave id 0..3
  const int nb   = wv * 32;           // wave's cout base
  const int lrow = lane & 15;
  const int lk8  = (lane >> 4) * 8;

  f32x4 acc[2][2];
#pragma unroll
  for (int i = 0; i < 2; ++i)
#pragma unroll
    for (int j = 0; j < 2; ++j) acc[i][j] = (f32x4){0.f, 0.f, 0.f, 0.f};

  __syncthreads();                    // As ready; no more barriers until epilogue

  // per-lane B row pointers (row n = nb[+16]+lrow, k-offset lk8), 16B-coalesced
  const unsigned short* wl0 = wt + (size_t)(nb + lrow) * 128 + lk8;
  const unsigned short* wl1 = wt + (size_t)(nb + 16 + lrow) * 128 + lk8;

  for (int tap = 0; tap < 9; ++tap) {
    const int r  = tap / 3;
    const int dc = tap % 3;
    const size_t to = (size_t)tap << 14;

#pragma unroll
    for (int kk = 0; kk < 64; kk += 32) {
      // A fragments (LDS), hi + lo planes
      bf16x8 ah0 = *(const bf16x8*)&As[r][lrow + dc][kk + lk8];
      bf16x8 ah1 = *(const bf16x8*)&As[r][16 + lrow + dc][kk + lk8];
      bf16x8 al0 = *(const bf16x8*)&As[r][lrow + dc][64 + kk + lk8];
      bf16x8 al1 = *(const bf16x8*)&As[r][16 + lrow + dc][64 + kk + lk8];
      // B fragments (global/L2), hi + lo planes
      bf16x8 bh0 = *(const bf16x8*)&wl0[to + kk];
      bf16x8 bh1 = *(const bf16x8*)&wl1[to + kk];
      bf16x8 bl0 = *(const bf16x8*)&wl0[to + 64 + kk];
      bf16x8 bl1 = *(const bf16x8*)&wl1[to + 64 + kk];

      // a*w ~= ah*wh + al*wh + ah*wl
      acc[0][0] = __builtin_amdgcn_mfma_f32_16x16x32_bf16(ah0, bh0, acc[0][0], 0, 0, 0);
      acc[0][1] = __builtin_amdgcn_mfma_f32_16x16x32_bf16(ah0, bh1, acc[0][1], 0, 0, 0);
      acc[1][0] = __builtin_amdgcn_mfma_f32_16x16x32_bf16(ah1, bh0, acc[1][0], 0, 0, 0);
      acc[1][1] = __builtin_amdgcn_mfma_f32_16x16x32_bf16(ah1, bh1, acc[1][1], 0, 0, 0);
      acc[0][0] = __builtin_amdgcn_mfma_f32_16x16x32_bf16(al0, bh0, acc[0][0], 0, 0, 0);
      acc[0][1] = __builtin_amdgcn_mfma_f32_16x16x32_bf16(al0, bh1, acc[0][1], 0, 0, 0);
      acc[1][0] = __builtin_amdgcn_mfma_f32_16x16x32_bf16(al1, bh0, acc[1][0], 0, 0, 0);
      acc[1][1] = __builtin_amdgcn_mfma_f32_16x16x32_bf16(al1, bh1, acc[1][1], 0, 0, 0);
      acc[0][0] = __builtin_amdgcn_mfma_f32_16x16x32_bf16(ah0, bl0, acc[0][0], 0, 0, 0);
      acc[0][1] = __builtin_amdgcn_mfma_f32_16x16x32_bf16(ah0, bl1, acc[0][1], 0, 0, 0);
      acc[1][0] = __builtin_amdgcn_mfma_f32_16x16x32_bf16(ah1, bl0, acc[1][0], 0, 0, 0);
      acc[1][1] = __builtin_amdgcn_mfma_f32_16x16x32_bf16(ah1, bl1, acc[1][1], 0, 0, 0);
    }
  }

  // ---- epilogue: bias + leaky, park gamma/beta in LDS (overlaid on As)
  __syncthreads();                     // all MFMA input reads complete
#pragma unroll
  for (int nf = 0; nf < 2; ++nf) {
    const int n = nb + nf * 16 + lrow;
    const float bias = (n < C) ? gbias[n] : bbias[n - C];
#pragma unroll
    for (int mf = 0; mf < 2; ++mf) {
#pragma unroll
      for (int rr = 0; rr < 4; ++rr) {
        int m = mf * 16 + (lane >> 4) * 4 + rr;   // D: row=(lane>>4)*4+reg
        float v = acc[mf][nf][rr] + bias;         //    col=lane&15
        g[m][n] = v > 0.f ? v : LEAKY * v;
      }
    }
  }
  __syncthreads();

  // ---- phase 2: stream x -> out for the strip's 32 pixels (256 KB each way)
  // chunk idx4 = tid + 256*i: pixel = i>>1 (tid-invariant), channel offset
  // (4*idx4)&63 = (4*tid)&63 (iteration-invariant). Nontemporal: stream-once
  // (keeps harness-restored x L3-resident, out doesn't pollute).
  const int c0 = (tid * 4) & 63;
  const size_t pbase = (size_t)pix0 * 2048 + (size_t)tid * 4;
#pragma unroll 4
  for (int p = 0; p < 32; ++p) {
    f32x4 ga = *(const f32x4*)&g[p][c0];
    f32x4 be = *(const f32x4*)&g[p][64 + c0];
    size_t a = pbase + (size_t)p * 2048;
    f32x4 x0 = __builtin_nontemporal_load((const f32x4*)&x[a]);
    f32x4 x1 = __builtin_nontemporal_load((const f32x4*)&x[a + 1024]);
    f32x4 o0, o1;
#pragma unroll
    for (int e = 0; e < 4; ++e) {
      o0[e] = fmaf(ga[e], x0[e], be[e]);
      o1[e] = fmaf(ga[e], x1[e], be[e]);
    }
    __builtin_nontemporal_store(o0, (f32x4*)&out[a]);
    __builtin_nontemporal_store(o1, (f32x4*)&out[a + 1024]);
  }
}

// ---------------------------------------------------------------------------
// Last-resort fallback (ws too small for even the 0.3 MB weight buffer):
// fused per-pixel conv + apply, zero workspace.
// ---------------------------------------------------------------------------
__global__ __launch_bounds__(256) void film_fused_slow(
    const float* __restrict__ psi,
    const float* __restrict__ gw, const float* __restrict__ gbias,
    const float* __restrict__ bw, const float* __restrict__ bbias,
    const float* __restrict__ x,
    float* __restrict__ out)
{
  const int pix = blockIdx.x;
  const int w = pix % Wc;
  const int h = (pix / Wc) % Hc;
  const int b = pix / (Wc * Hc);
  __shared__ float pshal[9 * CPSI];
  __shared__ float g[COUT2];
  const int t = threadIdx.x;

  if (t < 144) {
    int j = t * 4;
    int k = j % CPSI;
    int tap = j / CPSI;
    int r = tap / 3, s = tap % 3;
    int hh = h + r - 1, ww = w + s - 1;
    float4 v = make_float4(0.f, 0.f, 0.f, 0.f);
    if (hh >= 0 && hh < Hc && ww >= 0 && ww < Wc)
      v = *(const float4*)&psi[(((size_t)b * Hc + hh) * Wc + ww) * CPSI + k];
    *(float4*)&pshal[j] = v;
  }
  __syncthreads();

  if (t < COUT2) {
    int c = t & 63;
    const float* W_ = (t < C) ? gw : bw;
    float acc = (t < C) ? gbias[c] : bbias[c];
#pragma unroll 4
    for (int j = 0; j < 576; ++j) acc = fmaf(pshal[j], W_[(size_t)j * 64 + c], acc);
    g[t] = acc > 0.f ? acc : LEAKY * acc;
  }
  __syncthreads();

  const int coff = (t & 7) * 8;
  const size_t base = (size_t)pix * (BANDS * C) + (size_t)t * 8;
  float4 x0 = *(const float4*)&x[base];
  float4 x1 = *(const float4*)&x[base + 4];
  float4 ga0 = *(const float4*)&g[coff];
  float4 ga1 = *(const float4*)&g[coff + 4];
  float4 be0 = *(const float4*)&g[C + coff];
  float4 be1 = *(const float4*)&g[C + coff + 4];
  float4 o0, o1;
  o0.x = fmaf(ga0.x, x0.x, be0.x);
  o0.y = fmaf(ga0.y, x0.y, be0.y);
  o0.z = fmaf(ga0.z, x0.z, be0.z);
  o0.w = fmaf(ga0.w, x0.w, be0.w);
  o1.x = fmaf(ga1.x, x1.x, be1.x);
  o1.y = fmaf(ga1.y, x1.y, be1.y);
  o1.z = fmaf(ga1.z, x1.z, be1.z);
  o1.w = fmaf(ga1.w, x1.w, be1.w);
  *(float4*)&out[base] = o0;
  *(float4*)&out[base + 4] = o1;
}

extern "C" void kernel_launch(void* const* d_in, const int* in_sizes, int n_in,
                              void* d_out, int out_size, void* d_ws, size_t ws_size,
                              hipStream_t stream) {
  const float* x     = (const float*)d_in[0];
  const float* psi   = (const float*)d_in[1];
  const float* gw    = (const float*)d_in[2];
  const float* gbias = (const float*)d_in[3];
  const float* bw    = (const float*)d_in[4];
  const float* bbias = (const float*)d_in[5];
  float* out = (float*)d_out;

  const size_t wsplit_bytes = (size_t)9 * 128 * 128 * 2;   // 0.29 MB

  if (ws_size >= wsplit_bytes) {
    unsigned short* wtp = (unsigned short*)d_ws;
    split_w<<<9 * 128 * 128 / 256, 256, 0, stream>>>(gw, bw, wtp);
    sft_fused<<<NPIX / 32, 256, 0, stream>>>(psi, wtp, gbias, bbias, x, out);
  } else {
    film_fused_slow<<<NPIX, 256, 0, stream>>>(psi, gw, gbias, bw, bbias, x, out);
  }
}